// Round 15
// baseline (1887.363 us; speedup 1.0000x reference)
//
#include <hip/hip_runtime.h>

#define E_N 100000
#define NV_N 50000
#define NG_N 2000
#define EP 100096   // edges padded to 391*256
#define NTILES 391
#define NBIG 28     // tiles 0..27 split x3 (big units first); rest x4 -> 1536 units

typedef short s8v __attribute__((ext_vector_type(8)));
typedef unsigned short u16x8 __attribute__((ext_vector_type(8)));
typedef unsigned short u16x4 __attribute__((ext_vector_type(4)));
typedef unsigned int u32x4 __attribute__((ext_vector_type(4)));
typedef float f32x4 __attribute__((ext_vector_type(4)));

__device__ __forceinline__ float bf2f(unsigned short u) {
  return __uint_as_float(((unsigned int)u) << 16);
}
__device__ __forceinline__ unsigned short f2bf(float f) {
  unsigned int u = __float_as_uint(f);
  u = u + 0x7fffu + ((u >> 16) & 1u);   // RNE
  return (unsigned short)(u >> 16);
}

// ---------------- precompute kernels ----------------

// tabs: [4][256][1024] bf16. tb0: W1a rows0-7 + b1a; tb1: rows8-15; tb2/tb3: W2a.
__global__ void k_tables(const float* __restrict__ W1a, const float* __restrict__ b1a,
                         const float* __restrict__ W2a, const float* __restrict__ b2a,
                         unsigned short* __restrict__ tabs) {
  int tid = blockIdx.x * 256 + threadIdx.x;
  int tb = tid >> 18, v = (tid >> 10) & 255, k = tid & 1023;
  const float* W = (tb < 2) ? W1a : W2a;
  int rbase = (tb & 1) ? 8 : 0;
  float s = 0.f;
  if ((tb & 1) == 0) s = (tb < 2) ? b1a[k] : b2a[k];
  #pragma unroll
  for (int j = 0; j < 8; ++j)
    if ((v >> (7 - j)) & 1) s += W[(rbase + j) * 1024 + k];
  tabs[tid] = f2bf(s);
}

// Pack W[k][n] (K=1024, fp32) into MFMA-fragment streaming order for KC=64:
// fi = ((q*(N/32) + cb)*2 + ks)*2 + nf ; lane slot r = lg*16+ll holds
// k = q*64+ks*32+lg*8+u, n = cb*32+nf*16+ll. Each frag = 1KB contiguous.
// For wave wc, cb = 2*np+wc: stream strictly sequential (+4096 shorts/np).
__global__ void k_pack(const float* __restrict__ src, unsigned short* __restrict__ dst, int N) {
  int tid = blockIdx.x * 256 + threadIdx.x;
  int total = (1024 / 8) * N;
  if (tid >= total) return;
  int fi = tid >> 6, r = tid & 63;
  int lg = r >> 4, ll = r & 15;
  int nf = fi & 1, ks = (fi >> 1) & 1;
  int rest = fi >> 2;
  int nc32 = N / 32;
  int cb = rest % nc32, q = rest / nc32;
  int k0 = q * 64 + ks * 32 + lg * 8;
  int n = cb * 32 + nf * 16 + ll;
  u16x8 v;
  #pragma unroll
  for (int u = 0; u < 8; ++u)
    v[u] = f2bf(src[(size_t)(k0 + u) * N + n]);
  *(u16x8*)&dst[(size_t)tid * 8] = v;
}

__global__ void k_count(const int* __restrict__ ei, int* __restrict__ cnt) {
  int e = blockIdx.x * 256 + threadIdx.x;
  if (e < E_N) atomicAdd(&cnt[ei[E_N + e]], 1);
}

// ---------------- fused edge NNConv kernel ----------------
// r14 structure (256 thr, 256 edges/tile, KC=64, 2-half B-reuse, mixed
// x4/x3 K-split to 1536 units). NEW: sXT stored as bf16 (16.9KB vs 33KB
// fp32) -> block LDS ~52KB -> 3 blocks/CU (launch_bounds(256,3), VGPR cap
// 168 > 112) -> 3 waves/SIMD mutually hide the per-np latency bubbles that
// capped MfmaUtil at 46%. 1536 units on 768 slots = exactly 2/slot.
template<int NCOLS, int FOUT>
__global__ void __launch_bounds__(256, 3)
k_edge(const float* __restrict__ xsrc, const int* __restrict__ ei,
       const int* __restrict__ eap,
       const unsigned short* __restrict__ tab0,
       const unsigned short* __restrict__ tab1,
       const unsigned short* __restrict__ WP,     // packed B (+64KB guard)
       const float* __restrict__ bvec,            // theta bias [NCOLS] fp32
       float* __restrict__ agg)                   // [NV][FOUT] fp32, pre-zeroed
{
  constexpr int NP = NCOLS / 64;                  // 64-col passes per chunk

  __shared__ unsigned short sHid[256 * 64];       // 32KB, swizzled kb^(m&7)
  __shared__ unsigned short sXTh[32 * 264];       // 16.9KB bf16 x^T: [i][row]
  __shared__ int sSrc[256], sDst[256];
  __shared__ unsigned char sb0[256], sb1[256];

  const int t = threadIdx.x;
  const int l = t & 63;
  const int wid = t >> 6;
  const int wr = wid >> 1;          // 0..1 row sub-quarter
  const int wc = wid & 1;           // 0..1 col half
  const int lg = l >> 4;            // 0..3
  const int ll = l & 15;

  // ---- unit mapping: 84 big (x3) units first, then 1452 x4 units ----
  int tile, part, q0, q1;
  {
    const int bid = blockIdx.x;
    if (bid < 3 * NBIG) {
      tile = bid / 3; part = bid - tile * 3;
      q0 = (part == 0) ? 0 : (part == 1 ? 6 : 11);
      q1 = (part == 0) ? 6 : (part == 1 ? 11 : 16);
    } else {
      int v = bid - 3 * NBIG;
      tile = NBIG + (v >> 2); part = v & 3;
      q0 = part * 4; q1 = q0 + 4;
    }
  }
  const int e0 = tile * 256;

  // bf16x4 LDS x-read -> f32x4 (broadcast within lg-group, conflict-free)
  auto ldx = [&](int iidx, int rowbase) -> f32x4 {
    u16x4 u = *(const u16x4*)&sXTh[iidx * 264 + rowbase];
    f32x4 r;
    r[0] = bf2f(u[0]); r[1] = bf2f(u[1]); r[2] = bf2f(u[2]); r[3] = bf2f(u[3]);
    return r;
  };

  // build hidden chunk q (k in [q*64, q*64+64)) into sHid, all 256 rows
  auto build = [&](int q) {
    const unsigned short* p0 = tab0 + (size_t)sb0[t] * 1024 + q * 64;
    const unsigned short* p1 = tab1 + (size_t)sb1[t] * 1024 + q * 64;
    #pragma unroll
    for (int j = 0; j < 8; ++j) {
      u16x8 a = *(const u16x8*)(p0 + j * 8);
      u16x8 b = *(const u16x8*)(p1 + j * 8);
      u32x4 hw;
      #pragma unroll
      for (int p = 0; p < 4; ++p) {
        float f0 = fmaxf(bf2f(a[2 * p]) + bf2f(b[2 * p]), 0.f);
        float f1 = fmaxf(bf2f(a[2 * p + 1]) + bf2f(b[2 * p + 1]), 0.f);
        unsigned int r01;
        asm("v_cvt_pk_bf16_f32 %0, %1, %2" : "=v"(r01) : "v"(f0), "v"(f1));
        hw[p] = r01;
      }
      *(u32x4*)&sHid[t * 64 + 8 * (j ^ (t & 7))] = hw;
    }
  };

  // ---- B stream: one sequential pointer, +4096 shorts per np ----
  const unsigned short* bp = WP + (size_t)q0 * (NCOLS / 32) * 2048
                                + (size_t)wc * 2048 + (size_t)l * 8;
  s8v rb[2][2];                     // [ks][nf]
  rb[0][0] = *(const s8v*)bp;
  rb[0][1] = *(const s8v*)(bp + 512);
  rb[1][0] = *(const s8v*)(bp + 1024);
  rb[1][1] = *(const s8v*)(bp + 1536);
  bp += 4096;

  {
    int e = e0 + t;
    if (e < E_N) {
      sSrc[t] = ei[e]; sDst[t] = ei[E_N + e];
      sb0[t] = (unsigned char)(eap[2 * e] & 255);
      sb1[t] = (unsigned char)(eap[2 * e + 1] & 255);
    } else { sSrc[t] = 0; sDst[t] = -1; sb0[t] = 0; sb1[t] = 0; }
  }
  __syncthreads();
  for (int j = t; j < 256 * 32; j += 256) {
    int m = j >> 5, i = j & 31;
    float v = (e0 + m < E_N) ? xsrc[(size_t)sSrc[m] * 32 + i] : 0.f;
    sXTh[i * 264 + m] = f2bf(v);
  }
  build(q0);
  __syncthreads();

  f32x4 msgr[2][4][2] = {};         // [half][mf][nf], lanes over r

  #pragma unroll 1
  for (int q = q0; q < q1; ++q) {
    if (q > q0) {
      __syncthreads();              // all prior sHid reads done
      build(q);
      __syncthreads();
    }
    // hoist A fragments for both halves of the 64-K chunk; PIN so the
    // compiler cannot sink the ds_reads back into the np loop.
    s8v av[2][4][2];
    #pragma unroll
    for (int hf = 0; hf < 2; ++hf)
      #pragma unroll
      for (int mf = 0; mf < 4; ++mf) {
        int row = hf * 128 + wr * 64 + mf * 16 + ll;
        #pragma unroll
        for (int ks = 0; ks < 2; ++ks) {
          int kb = ks * 4 + lg;
          av[hf][mf][ks] = *(const s8v*)&sHid[row * 64 + 8 * (kb ^ (row & 7))];
          asm volatile("" : "+v"(av[hf][mf][ks]));
        }
      }
    #pragma unroll 1
    for (int np = 0; np < NP; ++np) {
      const int iidx = (FOUT == 64) ? np : np * 2 + wc;
      f32x4 acc[4][2];
      f32x4 xv[4];
      // ================= half 0 =================
      #pragma unroll
      for (int mf = 0; mf < 4; ++mf)
        xv[mf] = ldx(iidx, wr * 64 + mf * 16 + lg * 4);
      __builtin_amdgcn_s_setprio(1);
      #pragma unroll
      for (int mf = 0; mf < 4; ++mf)
        #pragma unroll
        for (int nf = 0; nf < 2; ++nf)
          acc[mf][nf] = __builtin_amdgcn_mfma_f32_16x16x32_bf16(
              av[0][mf][0], rb[0][nf], (f32x4){0.f, 0.f, 0.f, 0.f}, 0, 0, 0);
      #pragma unroll
      for (int mf = 0; mf < 4; ++mf)
        #pragma unroll
        for (int nf = 0; nf < 2; ++nf)
          acc[mf][nf] = __builtin_amdgcn_mfma_f32_16x16x32_bf16(
              av[0][mf][1], rb[1][nf], acc[mf][nf], 0, 0, 0);
      __builtin_amdgcn_s_setprio(0);
      #pragma unroll
      for (int mf = 0; mf < 4; ++mf) {
        msgr[0][mf][0] += acc[mf][0] * xv[mf];
        msgr[0][mf][1] += acc[mf][1] * xv[mf];
      }
      // ================= half 1 (same B fragments) =================
      #pragma unroll
      for (int mf = 0; mf < 4; ++mf)
        xv[mf] = ldx(iidx, 128 + wr * 64 + mf * 16 + lg * 4);
      __builtin_amdgcn_s_setprio(1);
      #pragma unroll
      for (int mf = 0; mf < 4; ++mf)
        #pragma unroll
        for (int nf = 0; nf < 2; ++nf)
          acc[mf][nf] = __builtin_amdgcn_mfma_f32_16x16x32_bf16(
              av[1][mf][0], rb[0][nf], (f32x4){0.f, 0.f, 0.f, 0.f}, 0, 0, 0);
      __builtin_amdgcn_s_setprio(0);
      rb[0][0] = *(const s8v*)bp;                 // rb[0] dead -> reload np+1
      rb[0][1] = *(const s8v*)(bp + 512);
      __builtin_amdgcn_s_setprio(1);
      #pragma unroll
      for (int mf = 0; mf < 4; ++mf)
        #pragma unroll
        for (int nf = 0; nf < 2; ++nf)
          acc[mf][nf] = __builtin_amdgcn_mfma_f32_16x16x32_bf16(
              av[1][mf][1], rb[1][nf], acc[mf][nf], 0, 0, 0);
      __builtin_amdgcn_s_setprio(0);
      rb[1][0] = *(const s8v*)(bp + 1024);        // rb[1] dead -> reload np+1
      rb[1][1] = *(const s8v*)(bp + 1536);
      bp += 4096;
      #pragma unroll
      for (int mf = 0; mf < 4; ++mf) {
        msgr[1][mf][0] += acc[mf][0] * xv[mf];
        msgr[1][mf][1] += acc[mf][1] * xv[mf];
      }
    }
  }

  // ---- bias term (part 0 only): msg += x @ reshape(bvec) ----
  // FOUT=32: (row,o) co-owned by both wc waves -> split i by parity (i%2==wc).
  if (part == 0) {
    #pragma unroll 4
    for (int i = 0; i < 32; ++i) {
      if (FOUT == 32 && (i & 1) != wc) continue;
      float w0, w1;
      {
        int ob = (FOUT == 64) ? wc * 32 : 0;
        w0 = bvec[i * FOUT + ob + ll];
        w1 = bvec[i * FOUT + ob + 16 + ll];
      }
      #pragma unroll
      for (int hf = 0; hf < 2; ++hf)
        #pragma unroll
        for (int mf = 0; mf < 4; ++mf) {
          f32x4 xv = ldx(i, hf * 128 + wr * 64 + mf * 16 + lg * 4);
          msgr[hf][mf][0] += xv * w0;
          msgr[hf][mf][1] += xv * w1;
        }
    }
  }

  // ---- epilogue: lane owns (row, o) pairs; scatter partial to agg[dst] ----
  #pragma unroll
  for (int hf = 0; hf < 2; ++hf)
    #pragma unroll
    for (int nf = 0; nf < 2; ++nf) {
      const int o = ((FOUT == 64) ? (wc * 2 + nf) * 16 : nf * 16) + ll;
      #pragma unroll
      for (int mf = 0; mf < 4; ++mf)
        #pragma unroll
        for (int r = 0; r < 4; ++r) {
          int row = hf * 128 + wr * 64 + mf * 16 + lg * 4 + r;
          int d = sDst[row];
          if (d >= 0) atomicAdd(&agg[(size_t)d * FOUT + o], msgr[hf][mf][nf][r]);
        }
    }
}

// ---------------- node update / pool / MLP ----------------

__global__ void k_node1(const float* __restrict__ x, const float* __restrict__ agg,
                        const int* __restrict__ cnt, const float* __restrict__ root,
                        const float* __restrict__ bias, float* __restrict__ h) {
  int tid = blockIdx.x * 256 + threadIdx.x;
  if (tid >= NV_N * 32) return;
  int n = tid >> 5, j = tid & 31;
  const float* xr = x + n * 32;
  float s = 0.f;
  #pragma unroll
  for (int i = 0; i < 32; ++i) s = fmaf(xr[i], root[i * 32 + j], s);
  int c = cnt[n]; if (c < 1) c = 1;
  h[tid] = fmaxf(agg[tid] / (float)c + s + bias[j], 0.f);
}

__global__ void k_node2(const float* __restrict__ hin, const float* __restrict__ agg,
                        const int* __restrict__ cnt, const float* __restrict__ root,
                        const float* __restrict__ bias, float* __restrict__ h2) {
  int tid = blockIdx.x * 256 + threadIdx.x;
  if (tid >= NV_N * 64) return;
  int n = tid >> 6, j = tid & 63;
  const float* xr = hin + n * 32;
  float s = 0.f;
  #pragma unroll
  for (int i = 0; i < 32; ++i) s = fmaf(xr[i], root[i * 64 + j], s);
  int c = cnt[n]; if (c < 1) c = 1;
  h2[tid] = fmaxf(agg[tid] / (float)c + s + bias[j], 0.f);
}

__device__ __forceinline__ int lowerb(const int* __restrict__ a, int n, int key) {
  int lo = 0, hi = n;
  while (lo < hi) { int mid = (lo + hi) >> 1; if (a[mid] < key) lo = mid + 1; else hi = mid; }
  return lo;
}

__global__ void k_pool(const float* __restrict__ h2, const int* __restrict__ batch,
                       float* __restrict__ g) {
  int gid = (blockIdx.x * 256 + threadIdx.x) >> 6;
  int l = threadIdx.x & 63;
  if (gid >= NG_N) return;
  int lo = lowerb(batch, NV_N, gid);
  int hi = lowerb(batch, NV_N, gid + 1);
  float s = 0.f;
  for (int n = lo; n < hi; ++n) s += h2[n * 64 + l];
  int c = hi - lo; if (c < 1) c = 1;
  g[gid * 64 + l] = s / (float)c;
}

template<int K, bool RELU>
__global__ void k_fc(const float* __restrict__ A, const float* __restrict__ W,
                     const float* __restrict__ bias, float* __restrict__ out, int N) {
  __shared__ float sA[8][K];
  int r0 = blockIdx.x * 8;
  int n = blockIdx.y * 256 + threadIdx.x;
  for (int j = threadIdx.x; j < 8 * K; j += 256) {
    int rr = j / K, kk = j - rr * K;
    int r = r0 + rr;
    sA[rr][kk] = (r < NG_N) ? A[r * K + kk] : 0.f;
  }
  __syncthreads();
  float acc[8] = {0.f, 0.f, 0.f, 0.f, 0.f, 0.f, 0.f, 0.f};
  for (int k = 0; k < K; ++k) {
    float b = W[k * N + n];
    #pragma unroll
    for (int rr = 0; rr < 8; ++rr) acc[rr] = fmaf(sA[rr][k], b, acc[rr]);
  }
  float bs = bias[n];
  #pragma unroll
  for (int rr = 0; rr < 8; ++rr) {
    int r = r0 + rr;
    if (r < NG_N) {
      float v = acc[rr] + bs;
      if (RELU) v = fmaxf(v, 0.f);
      out[r * N + n] = v;
    }
  }
}

__global__ void k_fc4(const float* __restrict__ A, const float* __restrict__ W,
                      const float* __restrict__ bias, float* __restrict__ out) {
  int tid = blockIdx.x * 256 + threadIdx.x;
  int r = tid >> 2, s = tid & 3;
  if (r >= NG_N || s >= 3) return;
  float acc = bias[s];
  for (int k = 0; k < 256; ++k) acc = fmaf(A[r * 256 + k], W[k * 3 + s], acc);
  out[r * 3 + s] = acc;
}

// ---------------- launch ----------------

extern "C" void kernel_launch(void* const* d_in, const int* in_sizes, int n_in,
                              void* d_out, int out_size, void* d_ws, size_t ws_size,
                              hipStream_t stream) {
  const float* x     = (const float*)d_in[0];
  const int*   ei    = (const int*)d_in[1];
  const int*   eap   = (const int*)d_in[2];
  const int*   batch = (const int*)d_in[3];
  const float* W1a   = (const float*)d_in[4];
  const float* b1a   = (const float*)d_in[5];
  const float* W1b   = (const float*)d_in[6];
  const float* b1b   = (const float*)d_in[7];
  const float* W2a   = (const float*)d_in[8];
  const float* b2a   = (const float*)d_in[9];
  const float* W2b   = (const float*)d_in[10];
  const float* b2b   = (const float*)d_in[11];
  const float* root1 = (const float*)d_in[12];
  const float* bias1 = (const float*)d_in[13];
  const float* root2 = (const float*)d_in[14];
  const float* bias2 = (const float*)d_in[15];
  const float* fcW1  = (const float*)d_in[16];
  const float* fcb1  = (const float*)d_in[17];
  const float* fcW2  = (const float*)d_in[18];
  const float* fcb2  = (const float*)d_in[19];
  const float* fcW3  = (const float*)d_in[20];
  const float* fcb3  = (const float*)d_in[21];
  const float* fcW4  = (const float*)d_in[22];
  const float* fcb4  = (const float*)d_in[23];
  float* out = (float*)d_out;

  char* w = (char*)d_ws;
  size_t off = 0;
  auto take = [&](size_t bytes) -> void* {
    void* p = w + off;
    off = (off + bytes + 255) & ~(size_t)255;
    return p;
  };
  unsigned short* tabs = (unsigned short*)take(4 * 256 * 1024 * 2);
  unsigned short* w1p  = (unsigned short*)take((size_t)1024 * 1024 * 2 + 65536);
  unsigned short* w2p  = (unsigned short*)take((size_t)1024 * 2048 * 2 + 65536);
  float* agg1 = (float*)take((size_t)NV_N * 32 * 4);
  float* agg2 = (float*)take((size_t)NV_N * 64 * 4);
  int*   cnt  = (int*)take((size_t)NV_N * 4);
  float* h    = (float*)take((size_t)NV_N * 32 * 4);
  float* h2   = (float*)take((size_t)NV_N * 64 * 4);
  float* g    = (float*)take((size_t)NG_N * 64 * 4);
  float* l1   = (float*)take((size_t)NG_N * 512 * 4);
  float* l2   = (float*)take((size_t)NG_N * 512 * 4);
  float* l3   = (float*)take((size_t)NG_N * 256 * 4);

  hipMemsetAsync(agg1, 0, (size_t)NV_N * 32 * 4, stream);
  hipMemsetAsync(agg2, 0, (size_t)NV_N * 64 * 4, stream);
  hipMemsetAsync(cnt, 0, (size_t)NV_N * 4, stream);

  k_tables<<<4096, 256, 0, stream>>>(W1a, b1a, W2a, b2a, tabs);
  k_pack<<<(1024 * 1024 / 8 + 255) / 256, 256, 0, stream>>>(W1b, w1p, 1024);
  k_pack<<<(1024 * 2048 / 8 + 255) / 256, 256, 0, stream>>>(W2b, w2p, 2048);
  k_count<<<(E_N + 255) / 256, 256, 0, stream>>>(ei, cnt);

  const int nblk = 3 * NBIG + 4 * (NTILES - NBIG);   // 1536 = 2*768 units
  k_edge<1024, 32><<<nblk, 256, 0, stream>>>(x, ei, eap, tabs, tabs + 262144,
                                             w1p, b1b, agg1);
  k_node1<<<(NV_N * 32) / 256, 256, 0, stream>>>(x, agg1, cnt, root1, bias1, h);

  k_edge<2048, 64><<<nblk, 256, 0, stream>>>(h, ei, eap, tabs + 2 * 262144, tabs + 3 * 262144,
                                             w2p, b2b, agg2);
  k_node2<<<(NV_N * 64) / 256, 256, 0, stream>>>(h, agg2, cnt, root2, bias2, h2);

  k_pool<<<(NG_N * 64) / 256, 256, 0, stream>>>(h2, batch, g);

  k_fc<64, true><<<dim3((NG_N + 7) / 8, 2), 256, 0, stream>>>(g, fcW1, fcb1, l1, 512);
  k_fc<512, true><<<dim3((NG_N + 7) / 8, 2), 256, 0, stream>>>(l1, fcW2, fcb2, l2, 512);
  k_fc<512, true><<<dim3((NG_N + 7) / 8, 1), 256, 0, stream>>>(l2, fcW3, fcb3, l3, 256);
  k_fc4<<<(NG_N * 4 + 255) / 256, 256, 0, stream>>>(l3, fcW4, fcb4, out);
}

// Round 16
// 826.745 us; speedup vs baseline: 2.2829x; 2.2829x over previous
//
#include <hip/hip_runtime.h>

#define E_N 100000
#define NV_N 50000
#define NG_N 2000
#define EP 100096   // edges padded to 391*256
#define NTILES 391
#define NBIG 28     // tiles 0..27 split x3 (big units first); rest x4 -> 1536 units

typedef short s8v __attribute__((ext_vector_type(8)));
typedef unsigned short u16x8 __attribute__((ext_vector_type(8)));
typedef unsigned short u16x4 __attribute__((ext_vector_type(4)));
typedef unsigned int u32x4 __attribute__((ext_vector_type(4)));
typedef float f32x4 __attribute__((ext_vector_type(4)));

__device__ __forceinline__ float bf2f(unsigned short u) {
  return __uint_as_float(((unsigned int)u) << 16);
}
__device__ __forceinline__ unsigned short f2bf(float f) {
  unsigned int u = __float_as_uint(f);
  u = u + 0x7fffu + ((u >> 16) & 1u);   // RNE
  return (unsigned short)(u >> 16);
}

// ---------------- precompute kernels ----------------

// tabs: [4][256][1024] bf16. tb0: W1a rows0-7 + b1a; tb1: rows8-15; tb2/tb3: W2a.
__global__ void k_tables(const float* __restrict__ W1a, const float* __restrict__ b1a,
                         const float* __restrict__ W2a, const float* __restrict__ b2a,
                         unsigned short* __restrict__ tabs) {
  int tid = blockIdx.x * 256 + threadIdx.x;
  int tb = tid >> 18, v = (tid >> 10) & 255, k = tid & 1023;
  const float* W = (tb < 2) ? W1a : W2a;
  int rbase = (tb & 1) ? 8 : 0;
  float s = 0.f;
  if ((tb & 1) == 0) s = (tb < 2) ? b1a[k] : b2a[k];
  #pragma unroll
  for (int j = 0; j < 8; ++j)
    if ((v >> (7 - j)) & 1) s += W[(rbase + j) * 1024 + k];
  tabs[tid] = f2bf(s);
}

// Pack W[k][n] (K=1024, fp32) into MFMA-fragment streaming order for KC=64:
// fi = ((q*(N/32) + cb)*2 + ks)*2 + nf ; lane slot r = lg*16+ll holds
// k = q*64+ks*32+lg*8+u, n = cb*32+nf*16+ll. Each frag = 1KB contiguous.
// For wave wc, cb = 2*np+wc: stream strictly sequential (+4096 shorts/np).
__global__ void k_pack(const float* __restrict__ src, unsigned short* __restrict__ dst, int N) {
  int tid = blockIdx.x * 256 + threadIdx.x;
  int total = (1024 / 8) * N;
  if (tid >= total) return;
  int fi = tid >> 6, r = tid & 63;
  int lg = r >> 4, ll = r & 15;
  int nf = fi & 1, ks = (fi >> 1) & 1;
  int rest = fi >> 2;
  int nc32 = N / 32;
  int cb = rest % nc32, q = rest / nc32;
  int k0 = q * 64 + ks * 32 + lg * 8;
  int n = cb * 32 + nf * 16 + ll;
  u16x8 v;
  #pragma unroll
  for (int u = 0; u < 8; ++u)
    v[u] = f2bf(src[(size_t)(k0 + u) * N + n]);
  *(u16x8*)&dst[(size_t)tid * 8] = v;
}

__global__ void k_count(const int* __restrict__ ei, int* __restrict__ cnt) {
  int e = blockIdx.x * 256 + threadIdx.x;
  if (e < E_N) atomicAdd(&cnt[ei[E_N + e]], 1);
}

// ---------------- fused edge NNConv kernel ----------------
// r14 structure (256 thr, 256 edges/tile, KC=64, 2-half B-reuse, mixed
// x4/x3 K-split to 1536 units) + bf16 sXT (LDS 69->52KB). KEY: keep
// launch_bounds(256,2) so VGPR stays 112 (r15's (256,3) re-capped to 84 ->
// catastrophic spill); the 3rd block/CU is scheduled OPPORTUNISTICALLY
// (VGPR allows 4 waves/SIMD, LDS now allows 3 blocks) -> occupancy rises
// without touching codegen. 1536 units on 768 slots = exactly 2/slot.
template<int NCOLS, int FOUT>
__global__ void __launch_bounds__(256, 2)
k_edge(const float* __restrict__ xsrc, const int* __restrict__ ei,
       const int* __restrict__ eap,
       const unsigned short* __restrict__ tab0,
       const unsigned short* __restrict__ tab1,
       const unsigned short* __restrict__ WP,     // packed B (+64KB guard)
       const float* __restrict__ bvec,            // theta bias [NCOLS] fp32
       float* __restrict__ agg)                   // [NV][FOUT] fp32, pre-zeroed
{
  constexpr int NP = NCOLS / 64;                  // 64-col passes per chunk

  __shared__ unsigned short sHid[256 * 64];       // 32KB, swizzled kb^(m&7)
  __shared__ unsigned short sXTh[32 * 264];       // 16.9KB bf16 x^T: [i][row]
  __shared__ int sSrc[256], sDst[256];
  __shared__ unsigned char sb0[256], sb1[256];

  const int t = threadIdx.x;
  const int l = t & 63;
  const int wid = t >> 6;
  const int wr = wid >> 1;          // 0..1 row sub-quarter
  const int wc = wid & 1;           // 0..1 col half
  const int lg = l >> 4;            // 0..3
  const int ll = l & 15;

  // ---- unit mapping: 84 big (x3) units first, then 1452 x4 units ----
  int tile, part, q0, q1;
  {
    const int bid = blockIdx.x;
    if (bid < 3 * NBIG) {
      tile = bid / 3; part = bid - tile * 3;
      q0 = (part == 0) ? 0 : (part == 1 ? 6 : 11);
      q1 = (part == 0) ? 6 : (part == 1 ? 11 : 16);
    } else {
      int v = bid - 3 * NBIG;
      tile = NBIG + (v >> 2); part = v & 3;
      q0 = part * 4; q1 = q0 + 4;
    }
  }
  const int e0 = tile * 256;

  // bf16x4 LDS x-read -> f32x4 (broadcast within lg-group, conflict-free)
  auto ldx = [&](int iidx, int rowbase) -> f32x4 {
    u16x4 u = *(const u16x4*)&sXTh[iidx * 264 + rowbase];
    f32x4 r;
    r[0] = bf2f(u[0]); r[1] = bf2f(u[1]); r[2] = bf2f(u[2]); r[3] = bf2f(u[3]);
    return r;
  };

  // build hidden chunk q (k in [q*64, q*64+64)) into sHid, all 256 rows
  auto build = [&](int q) {
    const unsigned short* p0 = tab0 + (size_t)sb0[t] * 1024 + q * 64;
    const unsigned short* p1 = tab1 + (size_t)sb1[t] * 1024 + q * 64;
    #pragma unroll
    for (int j = 0; j < 8; ++j) {
      u16x8 a = *(const u16x8*)(p0 + j * 8);
      u16x8 b = *(const u16x8*)(p1 + j * 8);
      u32x4 hw;
      #pragma unroll
      for (int p = 0; p < 4; ++p) {
        float f0 = fmaxf(bf2f(a[2 * p]) + bf2f(b[2 * p]), 0.f);
        float f1 = fmaxf(bf2f(a[2 * p + 1]) + bf2f(b[2 * p + 1]), 0.f);
        unsigned int r01;
        asm("v_cvt_pk_bf16_f32 %0, %1, %2" : "=v"(r01) : "v"(f0), "v"(f1));
        hw[p] = r01;
      }
      *(u32x4*)&sHid[t * 64 + 8 * (j ^ (t & 7))] = hw;
    }
  };

  // ---- B stream: one sequential pointer, +4096 shorts per np ----
  const unsigned short* bp = WP + (size_t)q0 * (NCOLS / 32) * 2048
                                + (size_t)wc * 2048 + (size_t)l * 8;
  s8v rb[2][2];                     // [ks][nf]
  rb[0][0] = *(const s8v*)bp;
  rb[0][1] = *(const s8v*)(bp + 512);
  rb[1][0] = *(const s8v*)(bp + 1024);
  rb[1][1] = *(const s8v*)(bp + 1536);
  bp += 4096;

  {
    int e = e0 + t;
    if (e < E_N) {
      sSrc[t] = ei[e]; sDst[t] = ei[E_N + e];
      sb0[t] = (unsigned char)(eap[2 * e] & 255);
      sb1[t] = (unsigned char)(eap[2 * e + 1] & 255);
    } else { sSrc[t] = 0; sDst[t] = -1; sb0[t] = 0; sb1[t] = 0; }
  }
  __syncthreads();
  for (int j = t; j < 256 * 32; j += 256) {
    int m = j >> 5, i = j & 31;
    float v = (e0 + m < E_N) ? xsrc[(size_t)sSrc[m] * 32 + i] : 0.f;
    sXTh[i * 264 + m] = f2bf(v);
  }
  build(q0);
  __syncthreads();

  f32x4 msgr[2][4][2] = {};         // [half][mf][nf], lanes over r

  #pragma unroll 1
  for (int q = q0; q < q1; ++q) {
    if (q > q0) {
      __syncthreads();              // all prior sHid reads done
      build(q);
      __syncthreads();
    }
    // hoist A fragments for both halves of the 64-K chunk; PIN so the
    // compiler cannot sink the ds_reads back into the np loop.
    s8v av[2][4][2];
    #pragma unroll
    for (int hf = 0; hf < 2; ++hf)
      #pragma unroll
      for (int mf = 0; mf < 4; ++mf) {
        int row = hf * 128 + wr * 64 + mf * 16 + ll;
        #pragma unroll
        for (int ks = 0; ks < 2; ++ks) {
          int kb = ks * 4 + lg;
          av[hf][mf][ks] = *(const s8v*)&sHid[row * 64 + 8 * (kb ^ (row & 7))];
          asm volatile("" : "+v"(av[hf][mf][ks]));
        }
      }
    #pragma unroll 1
    for (int np = 0; np < NP; ++np) {
      const int iidx = (FOUT == 64) ? np : np * 2 + wc;
      f32x4 acc[4][2];
      f32x4 xv[4];
      // ================= half 0 =================
      #pragma unroll
      for (int mf = 0; mf < 4; ++mf)
        xv[mf] = ldx(iidx, wr * 64 + mf * 16 + lg * 4);
      __builtin_amdgcn_s_setprio(1);
      #pragma unroll
      for (int mf = 0; mf < 4; ++mf)
        #pragma unroll
        for (int nf = 0; nf < 2; ++nf)
          acc[mf][nf] = __builtin_amdgcn_mfma_f32_16x16x32_bf16(
              av[0][mf][0], rb[0][nf], (f32x4){0.f, 0.f, 0.f, 0.f}, 0, 0, 0);
      #pragma unroll
      for (int mf = 0; mf < 4; ++mf)
        #pragma unroll
        for (int nf = 0; nf < 2; ++nf)
          acc[mf][nf] = __builtin_amdgcn_mfma_f32_16x16x32_bf16(
              av[0][mf][1], rb[1][nf], acc[mf][nf], 0, 0, 0);
      __builtin_amdgcn_s_setprio(0);
      #pragma unroll
      for (int mf = 0; mf < 4; ++mf) {
        msgr[0][mf][0] += acc[mf][0] * xv[mf];
        msgr[0][mf][1] += acc[mf][1] * xv[mf];
      }
      // ================= half 1 (same B fragments) =================
      #pragma unroll
      for (int mf = 0; mf < 4; ++mf)
        xv[mf] = ldx(iidx, 128 + wr * 64 + mf * 16 + lg * 4);
      __builtin_amdgcn_s_setprio(1);
      #pragma unroll
      for (int mf = 0; mf < 4; ++mf)
        #pragma unroll
        for (int nf = 0; nf < 2; ++nf)
          acc[mf][nf] = __builtin_amdgcn_mfma_f32_16x16x32_bf16(
              av[1][mf][0], rb[0][nf], (f32x4){0.f, 0.f, 0.f, 0.f}, 0, 0, 0);
      __builtin_amdgcn_s_setprio(0);
      rb[0][0] = *(const s8v*)bp;                 // rb[0] dead -> reload np+1
      rb[0][1] = *(const s8v*)(bp + 512);
      __builtin_amdgcn_s_setprio(1);
      #pragma unroll
      for (int mf = 0; mf < 4; ++mf)
        #pragma unroll
        for (int nf = 0; nf < 2; ++nf)
          acc[mf][nf] = __builtin_amdgcn_mfma_f32_16x16x32_bf16(
              av[1][mf][1], rb[1][nf], acc[mf][nf], 0, 0, 0);
      __builtin_amdgcn_s_setprio(0);
      rb[1][0] = *(const s8v*)(bp + 1024);        // rb[1] dead -> reload np+1
      rb[1][1] = *(const s8v*)(bp + 1536);
      bp += 4096;
      #pragma unroll
      for (int mf = 0; mf < 4; ++mf) {
        msgr[1][mf][0] += acc[mf][0] * xv[mf];
        msgr[1][mf][1] += acc[mf][1] * xv[mf];
      }
    }
  }

  // ---- bias term (part 0 only): msg += x @ reshape(bvec) ----
  // FOUT=32: (row,o) co-owned by both wc waves -> split i by parity (i%2==wc).
  if (part == 0) {
    #pragma unroll 4
    for (int i = 0; i < 32; ++i) {
      if (FOUT == 32 && (i & 1) != wc) continue;
      float w0, w1;
      {
        int ob = (FOUT == 64) ? wc * 32 : 0;
        w0 = bvec[i * FOUT + ob + ll];
        w1 = bvec[i * FOUT + ob + 16 + ll];
      }
      #pragma unroll
      for (int hf = 0; hf < 2; ++hf)
        #pragma unroll
        for (int mf = 0; mf < 4; ++mf) {
          f32x4 xv = ldx(i, hf * 128 + wr * 64 + mf * 16 + lg * 4);
          msgr[hf][mf][0] += xv * w0;
          msgr[hf][mf][1] += xv * w1;
        }
    }
  }

  // ---- epilogue: lane owns (row, o) pairs; scatter partial to agg[dst] ----
  #pragma unroll
  for (int hf = 0; hf < 2; ++hf)
    #pragma unroll
    for (int nf = 0; nf < 2; ++nf) {
      const int o = ((FOUT == 64) ? (wc * 2 + nf) * 16 : nf * 16) + ll;
      #pragma unroll
      for (int mf = 0; mf < 4; ++mf)
        #pragma unroll
        for (int r = 0; r < 4; ++r) {
          int row = hf * 128 + wr * 64 + mf * 16 + lg * 4 + r;
          int d = sDst[row];
          if (d >= 0) atomicAdd(&agg[(size_t)d * FOUT + o], msgr[hf][mf][nf][r]);
        }
    }
}

// ---------------- node update / pool / MLP ----------------

__global__ void k_node1(const float* __restrict__ x, const float* __restrict__ agg,
                        const int* __restrict__ cnt, const float* __restrict__ root,
                        const float* __restrict__ bias, float* __restrict__ h) {
  int tid = blockIdx.x * 256 + threadIdx.x;
  if (tid >= NV_N * 32) return;
  int n = tid >> 5, j = tid & 31;
  const float* xr = x + n * 32;
  float s = 0.f;
  #pragma unroll
  for (int i = 0; i < 32; ++i) s = fmaf(xr[i], root[i * 32 + j], s);
  int c = cnt[n]; if (c < 1) c = 1;
  h[tid] = fmaxf(agg[tid] / (float)c + s + bias[j], 0.f);
}

__global__ void k_node2(const float* __restrict__ hin, const float* __restrict__ agg,
                        const int* __restrict__ cnt, const float* __restrict__ root,
                        const float* __restrict__ bias, float* __restrict__ h2) {
  int tid = blockIdx.x * 256 + threadIdx.x;
  if (tid >= NV_N * 64) return;
  int n = tid >> 6, j = tid & 63;
  const float* xr = hin + n * 32;
  float s = 0.f;
  #pragma unroll
  for (int i = 0; i < 32; ++i) s = fmaf(xr[i], root[i * 64 + j], s);
  int c = cnt[n]; if (c < 1) c = 1;
  h2[tid] = fmaxf(agg[tid] / (float)c + s + bias[j], 0.f);
}

__device__ __forceinline__ int lowerb(const int* __restrict__ a, int n, int key) {
  int lo = 0, hi = n;
  while (lo < hi) { int mid = (lo + hi) >> 1; if (a[mid] < key) lo = mid + 1; else hi = mid; }
  return lo;
}

__global__ void k_pool(const float* __restrict__ h2, const int* __restrict__ batch,
                       float* __restrict__ g) {
  int gid = (blockIdx.x * 256 + threadIdx.x) >> 6;
  int l = threadIdx.x & 63;
  if (gid >= NG_N) return;
  int lo = lowerb(batch, NV_N, gid);
  int hi = lowerb(batch, NV_N, gid + 1);
  float s = 0.f;
  for (int n = lo; n < hi; ++n) s += h2[n * 64 + l];
  int c = hi - lo; if (c < 1) c = 1;
  g[gid * 64 + l] = s / (float)c;
}

template<int K, bool RELU>
__global__ void k_fc(const float* __restrict__ A, const float* __restrict__ W,
                     const float* __restrict__ bias, float* __restrict__ out, int N) {
  __shared__ float sA[8][K];
  int r0 = blockIdx.x * 8;
  int n = blockIdx.y * 256 + threadIdx.x;
  for (int j = threadIdx.x; j < 8 * K; j += 256) {
    int rr = j / K, kk = j - rr * K;
    int r = r0 + rr;
    sA[rr][kk] = (r < NG_N) ? A[r * K + kk] : 0.f;
  }
  __syncthreads();
  float acc[8] = {0.f, 0.f, 0.f, 0.f, 0.f, 0.f, 0.f, 0.f};
  for (int k = 0; k < K; ++k) {
    float b = W[k * N + n];
    #pragma unroll
    for (int rr = 0; rr < 8; ++rr) acc[rr] = fmaf(sA[rr][k], b, acc[rr]);
  }
  float bs = bias[n];
  #pragma unroll
  for (int rr = 0; rr < 8; ++rr) {
    int r = r0 + rr;
    if (r < NG_N) {
      float v = acc[rr] + bs;
      if (RELU) v = fmaxf(v, 0.f);
      out[r * N + n] = v;
    }
  }
}

__global__ void k_fc4(const float* __restrict__ A, const float* __restrict__ W,
                      const float* __restrict__ bias, float* __restrict__ out) {
  int tid = blockIdx.x * 256 + threadIdx.x;
  int r = tid >> 2, s = tid & 3;
  if (r >= NG_N || s >= 3) return;
  float acc = bias[s];
  for (int k = 0; k < 256; ++k) acc = fmaf(A[r * 256 + k], W[k * 3 + s], acc);
  out[r * 3 + s] = acc;
}

// ---------------- launch ----------------

extern "C" void kernel_launch(void* const* d_in, const int* in_sizes, int n_in,
                              void* d_out, int out_size, void* d_ws, size_t ws_size,
                              hipStream_t stream) {
  const float* x     = (const float*)d_in[0];
  const int*   ei    = (const int*)d_in[1];
  const int*   eap   = (const int*)d_in[2];
  const int*   batch = (const int*)d_in[3];
  const float* W1a   = (const float*)d_in[4];
  const float* b1a   = (const float*)d_in[5];
  const float* W1b   = (const float*)d_in[6];
  const float* b1b   = (const float*)d_in[7];
  const float* W2a   = (const float*)d_in[8];
  const float* b2a   = (const float*)d_in[9];
  const float* W2b   = (const float*)d_in[10];
  const float* b2b   = (const float*)d_in[11];
  const float* root1 = (const float*)d_in[12];
  const float* bias1 = (const float*)d_in[13];
  const float* root2 = (const float*)d_in[14];
  const float* bias2 = (const float*)d_in[15];
  const float* fcW1  = (const float*)d_in[16];
  const float* fcb1  = (const float*)d_in[17];
  const float* fcW2  = (const float*)d_in[18];
  const float* fcb2  = (const float*)d_in[19];
  const float* fcW3  = (const float*)d_in[20];
  const float* fcb3  = (const float*)d_in[21];
  const float* fcW4  = (const float*)d_in[22];
  const float* fcb4  = (const float*)d_in[23];
  float* out = (float*)d_out;

  char* w = (char*)d_ws;
  size_t off = 0;
  auto take = [&](size_t bytes) -> void* {
    void* p = w + off;
    off = (off + bytes + 255) & ~(size_t)255;
    return p;
  };
  unsigned short* tabs = (unsigned short*)take(4 * 256 * 1024 * 2);
  unsigned short* w1p  = (unsigned short*)take((size_t)1024 * 1024 * 2 + 65536);
  unsigned short* w2p  = (unsigned short*)take((size_t)1024 * 2048 * 2 + 65536);
  float* agg1 = (float*)take((size_t)NV_N * 32 * 4);
  float* agg2 = (float*)take((size_t)NV_N * 64 * 4);
  int*   cnt  = (int*)take((size_t)NV_N * 4);
  float* h    = (float*)take((size_t)NV_N * 32 * 4);
  float* h2   = (float*)take((size_t)NV_N * 64 * 4);
  float* g    = (float*)take((size_t)NG_N * 64 * 4);
  float* l1   = (float*)take((size_t)NG_N * 512 * 4);
  float* l2   = (float*)take((size_t)NG_N * 512 * 4);
  float* l3   = (float*)take((size_t)NG_N * 256 * 4);

  hipMemsetAsync(agg1, 0, (size_t)NV_N * 32 * 4, stream);
  hipMemsetAsync(agg2, 0, (size_t)NV_N * 64 * 4, stream);
  hipMemsetAsync(cnt, 0, (size_t)NV_N * 4, stream);

  k_tables<<<4096, 256, 0, stream>>>(W1a, b1a, W2a, b2a, tabs);
  k_pack<<<(1024 * 1024 / 8 + 255) / 256, 256, 0, stream>>>(W1b, w1p, 1024);
  k_pack<<<(1024 * 2048 / 8 + 255) / 256, 256, 0, stream>>>(W2b, w2p, 2048);
  k_count<<<(E_N + 255) / 256, 256, 0, stream>>>(ei, cnt);

  const int nblk = 3 * NBIG + 4 * (NTILES - NBIG);   // 1536 = 2*768 units
  k_edge<1024, 32><<<nblk, 256, 0, stream>>>(x, ei, eap, tabs, tabs + 262144,
                                             w1p, b1b, agg1);
  k_node1<<<(NV_N * 32) / 256, 256, 0, stream>>>(x, agg1, cnt, root1, bias1, h);

  k_edge<2048, 64><<<nblk, 256, 0, stream>>>(h, ei, eap, tabs + 2 * 262144, tabs + 3 * 262144,
                                             w2p, b2b, agg2);
  k_node2<<<(NV_N * 64) / 256, 256, 0, stream>>>(h, agg2, cnt, root2, bias2, h2);

  k_pool<<<(NG_N * 64) / 256, 256, 0, stream>>>(h2, batch, g);

  k_fc<64, true><<<dim3((NG_N + 7) / 8, 2), 256, 0, stream>>>(g, fcW1, fcb1, l1, 512);
  k_fc<512, true><<<dim3((NG_N + 7) / 8, 2), 256, 0, stream>>>(l1, fcW2, fcb2, l2, 512);
  k_fc<512, true><<<dim3((NG_N + 7) / 8, 1), 256, 0, stream>>>(l2, fcW3, fcb3, l3, 256);
  k_fc4<<<(NG_N * 4 + 255) / 256, 256, 0, stream>>>(l3, fcW4, fcb4, out);
}

// Round 17
// 791.497 us; speedup vs baseline: 2.3845x; 1.0445x over previous
//
#include <hip/hip_runtime.h>

#define E_N 100000
#define NV_N 50000
#define NG_N 2000
#define EP 100096   // edges padded to 391*256
#define NTILES 391
#define NBIG 28     // tiles 0..27 split x3 (big units first); rest x4 -> 1536 units

typedef short s8v __attribute__((ext_vector_type(8)));
typedef unsigned short u16x8 __attribute__((ext_vector_type(8)));
typedef unsigned int u32x4 __attribute__((ext_vector_type(4)));
typedef float f32x4 __attribute__((ext_vector_type(4)));

__device__ __forceinline__ float bf2f(unsigned short u) {
  return __uint_as_float(((unsigned int)u) << 16);
}
__device__ __forceinline__ unsigned short f2bf(float f) {
  unsigned int u = __float_as_uint(f);
  u = u + 0x7fffu + ((u >> 16) & 1u);   // RNE
  return (unsigned short)(u >> 16);
}

// ---------------- precompute kernels ----------------

// tabs: [4][256][1024] bf16. tb0: W1a rows0-7 + b1a; tb1: rows8-15; tb2/tb3: W2a.
__global__ void k_tables(const float* __restrict__ W1a, const float* __restrict__ b1a,
                         const float* __restrict__ W2a, const float* __restrict__ b2a,
                         unsigned short* __restrict__ tabs) {
  int tid = blockIdx.x * 256 + threadIdx.x;
  int tb = tid >> 18, v = (tid >> 10) & 255, k = tid & 1023;
  const float* W = (tb < 2) ? W1a : W2a;
  int rbase = (tb & 1) ? 8 : 0;
  float s = 0.f;
  if ((tb & 1) == 0) s = (tb < 2) ? b1a[k] : b2a[k];
  #pragma unroll
  for (int j = 0; j < 8; ++j)
    if ((v >> (7 - j)) & 1) s += W[(rbase + j) * 1024 + k];
  tabs[tid] = f2bf(s);
}

// Pack W[k][n] (K=1024, fp32) into MFMA-fragment streaming order for KC=64:
// fi = ((q*(N/32) + cb)*2 + ks)*2 + nf ; lane slot r = lg*16+ll holds
// k = q*64+ks*32+lg*8+u, n = cb*32+nf*16+ll. Each frag = 1KB contiguous.
// For wave wc, cb = 2*np+wc: stream strictly sequential (+4096 shorts/np).
__global__ void k_pack(const float* __restrict__ src, unsigned short* __restrict__ dst, int N) {
  int tid = blockIdx.x * 256 + threadIdx.x;
  int total = (1024 / 8) * N;
  if (tid >= total) return;
  int fi = tid >> 6, r = tid & 63;
  int lg = r >> 4, ll = r & 15;
  int nf = fi & 1, ks = (fi >> 1) & 1;
  int rest = fi >> 2;
  int nc32 = N / 32;
  int cb = rest % nc32, q = rest / nc32;
  int k0 = q * 64 + ks * 32 + lg * 8;
  int n = cb * 32 + nf * 16 + ll;
  u16x8 v;
  #pragma unroll
  for (int u = 0; u < 8; ++u)
    v[u] = f2bf(src[(size_t)(k0 + u) * N + n]);
  *(u16x8*)&dst[(size_t)tid * 8] = v;
}

__global__ void k_count(const int* __restrict__ ei, int* __restrict__ cnt) {
  int e = blockIdx.x * 256 + threadIdx.x;
  if (e < E_N) atomicAdd(&cnt[ei[E_N + e]], 1);
}

// ---------------- fused edge NNConv kernel ----------------
// r14 configuration restored verbatim (best measured: 793us total).
// 256 thr = 4 waves (2 wr x 2 wc), 256 edges/tile, KC=64, 2-half B-reuse,
// mixed x4/x3 K-split to 1536 units (= 3*512 block-slots). Issue-bound
// steady state: MfmaUtil ~46%, VALUBusy ~30%; VALU pipe is the co-limit
// (r16's +32 VALU/np regressed; r13's deeper pipeline spilled).
template<int NCOLS, int FOUT>
__global__ void __launch_bounds__(256, 2)
k_edge(const float* __restrict__ xsrc, const int* __restrict__ ei,
       const int* __restrict__ eap,
       const unsigned short* __restrict__ tab0,
       const unsigned short* __restrict__ tab1,
       const unsigned short* __restrict__ WP,     // packed B (+64KB guard)
       const float* __restrict__ bvec,            // theta bias [NCOLS] fp32
       float* __restrict__ agg)                   // [NV][FOUT] fp32, pre-zeroed
{
  constexpr int NP = NCOLS / 64;                  // 64-col passes per chunk

  __shared__ unsigned short sHid[256 * 64];       // 32KB, swizzled kb^(m&7)
  __shared__ float sXT[32 * 264];                 // 33KB x^T: [i][row], pad 264
  __shared__ int sSrc[256], sDst[256];
  __shared__ unsigned char sb0[256], sb1[256];

  const int t = threadIdx.x;
  const int l = t & 63;
  const int wid = t >> 6;
  const int wr = wid >> 1;          // 0..1 row sub-quarter
  const int wc = wid & 1;           // 0..1 col half
  const int lg = l >> 4;            // 0..3
  const int ll = l & 15;

  // ---- unit mapping: 84 big (x3) units first, then 1452 x4 units ----
  int tile, part, q0, q1;
  {
    const int bid = blockIdx.x;
    if (bid < 3 * NBIG) {
      tile = bid / 3; part = bid - tile * 3;
      q0 = (part == 0) ? 0 : (part == 1 ? 6 : 11);
      q1 = (part == 0) ? 6 : (part == 1 ? 11 : 16);
    } else {
      int v = bid - 3 * NBIG;
      tile = NBIG + (v >> 2); part = v & 3;
      q0 = part * 4; q1 = q0 + 4;
    }
  }
  const int e0 = tile * 256;

  // build hidden chunk q (k in [q*64, q*64+64)) into sHid, all 256 rows
  auto build = [&](int q) {
    const unsigned short* p0 = tab0 + (size_t)sb0[t] * 1024 + q * 64;
    const unsigned short* p1 = tab1 + (size_t)sb1[t] * 1024 + q * 64;
    #pragma unroll
    for (int j = 0; j < 8; ++j) {
      u16x8 a = *(const u16x8*)(p0 + j * 8);
      u16x8 b = *(const u16x8*)(p1 + j * 8);
      u32x4 hw;
      #pragma unroll
      for (int p = 0; p < 4; ++p) {
        float f0 = fmaxf(bf2f(a[2 * p]) + bf2f(b[2 * p]), 0.f);
        float f1 = fmaxf(bf2f(a[2 * p + 1]) + bf2f(b[2 * p + 1]), 0.f);
        unsigned int r01;
        asm("v_cvt_pk_bf16_f32 %0, %1, %2" : "=v"(r01) : "v"(f0), "v"(f1));
        hw[p] = r01;
      }
      *(u32x4*)&sHid[t * 64 + 8 * (j ^ (t & 7))] = hw;
    }
  };

  // ---- B stream: one sequential pointer, +4096 shorts per np ----
  const unsigned short* bp = WP + (size_t)q0 * (NCOLS / 32) * 2048
                                + (size_t)wc * 2048 + (size_t)l * 8;
  s8v rb[2][2];                     // [ks][nf]
  rb[0][0] = *(const s8v*)bp;
  rb[0][1] = *(const s8v*)(bp + 512);
  rb[1][0] = *(const s8v*)(bp + 1024);
  rb[1][1] = *(const s8v*)(bp + 1536);
  bp += 4096;

  {
    int e = e0 + t;
    if (e < E_N) {
      sSrc[t] = ei[e]; sDst[t] = ei[E_N + e];
      sb0[t] = (unsigned char)(eap[2 * e] & 255);
      sb1[t] = (unsigned char)(eap[2 * e + 1] & 255);
    } else { sSrc[t] = 0; sDst[t] = -1; sb0[t] = 0; sb1[t] = 0; }
  }
  __syncthreads();
  for (int j = t; j < 256 * 32; j += 256) {
    int m = j >> 5, i = j & 31;
    sXT[i * 264 + m] = (e0 + m < E_N) ? xsrc[(size_t)sSrc[m] * 32 + i] : 0.f;
  }
  build(q0);
  __syncthreads();

  f32x4 msgr[2][4][2] = {};         // [half][mf][nf], lanes over r

  #pragma unroll 1
  for (int q = q0; q < q1; ++q) {
    if (q > q0) {
      __syncthreads();              // all prior sHid reads done
      build(q);
      __syncthreads();
    }
    // hoist A fragments for both halves of the 64-K chunk; PIN so the
    // compiler cannot sink the ds_reads back into the np loop.
    s8v av[2][4][2];
    #pragma unroll
    for (int hf = 0; hf < 2; ++hf)
      #pragma unroll
      for (int mf = 0; mf < 4; ++mf) {
        int row = hf * 128 + wr * 64 + mf * 16 + ll;
        #pragma unroll
        for (int ks = 0; ks < 2; ++ks) {
          int kb = ks * 4 + lg;
          av[hf][mf][ks] = *(const s8v*)&sHid[row * 64 + 8 * (kb ^ (row & 7))];
          asm volatile("" : "+v"(av[hf][mf][ks]));
        }
      }
    #pragma unroll 1
    for (int np = 0; np < NP; ++np) {
      const int iidx = (FOUT == 64) ? np : np * 2 + wc;
      f32x4 acc[4][2];
      f32x4 xv[4];
      // ================= half 0 =================
      #pragma unroll
      for (int mf = 0; mf < 4; ++mf)
        xv[mf] = *(const f32x4*)&sXT[iidx * 264 + wr * 64 + mf * 16 + lg * 4];
      __builtin_amdgcn_s_setprio(1);
      #pragma unroll
      for (int mf = 0; mf < 4; ++mf)
        #pragma unroll
        for (int nf = 0; nf < 2; ++nf)
          acc[mf][nf] = __builtin_amdgcn_mfma_f32_16x16x32_bf16(
              av[0][mf][0], rb[0][nf], (f32x4){0.f, 0.f, 0.f, 0.f}, 0, 0, 0);
      #pragma unroll
      for (int mf = 0; mf < 4; ++mf)
        #pragma unroll
        for (int nf = 0; nf < 2; ++nf)
          acc[mf][nf] = __builtin_amdgcn_mfma_f32_16x16x32_bf16(
              av[0][mf][1], rb[1][nf], acc[mf][nf], 0, 0, 0);
      __builtin_amdgcn_s_setprio(0);
      #pragma unroll
      for (int mf = 0; mf < 4; ++mf) {
        msgr[0][mf][0] += acc[mf][0] * xv[mf];
        msgr[0][mf][1] += acc[mf][1] * xv[mf];
      }
      // ================= half 1 (same B fragments) =================
      #pragma unroll
      for (int mf = 0; mf < 4; ++mf)
        xv[mf] = *(const f32x4*)&sXT[iidx * 264 + 128 + wr * 64 + mf * 16 + lg * 4];
      __builtin_amdgcn_s_setprio(1);
      #pragma unroll
      for (int mf = 0; mf < 4; ++mf)
        #pragma unroll
        for (int nf = 0; nf < 2; ++nf)
          acc[mf][nf] = __builtin_amdgcn_mfma_f32_16x16x32_bf16(
              av[1][mf][0], rb[0][nf], (f32x4){0.f, 0.f, 0.f, 0.f}, 0, 0, 0);
      __builtin_amdgcn_s_setprio(0);
      rb[0][0] = *(const s8v*)bp;                 // rb[0] dead -> reload np+1
      rb[0][1] = *(const s8v*)(bp + 512);
      __builtin_amdgcn_s_setprio(1);
      #pragma unroll
      for (int mf = 0; mf < 4; ++mf)
        #pragma unroll
        for (int nf = 0; nf < 2; ++nf)
          acc[mf][nf] = __builtin_amdgcn_mfma_f32_16x16x32_bf16(
              av[1][mf][1], rb[1][nf], acc[mf][nf], 0, 0, 0);
      __builtin_amdgcn_s_setprio(0);
      rb[1][0] = *(const s8v*)(bp + 1024);        // rb[1] dead -> reload np+1
      rb[1][1] = *(const s8v*)(bp + 1536);
      bp += 4096;
      #pragma unroll
      for (int mf = 0; mf < 4; ++mf) {
        msgr[1][mf][0] += acc[mf][0] * xv[mf];
        msgr[1][mf][1] += acc[mf][1] * xv[mf];
      }
    }
  }

  // ---- bias term (part 0 only): msg += x @ reshape(bvec) ----
  // FOUT=32: (row,o) co-owned by both wc waves -> split i by parity (i%2==wc).
  if (part == 0) {
    #pragma unroll 4
    for (int i = 0; i < 32; ++i) {
      if (FOUT == 32 && (i & 1) != wc) continue;
      float w0, w1;
      {
        int ob = (FOUT == 64) ? wc * 32 : 0;
        w0 = bvec[i * FOUT + ob + ll];
        w1 = bvec[i * FOUT + ob + 16 + ll];
      }
      #pragma unroll
      for (int hf = 0; hf < 2; ++hf)
        #pragma unroll
        for (int mf = 0; mf < 4; ++mf) {
          f32x4 xv = *(const f32x4*)&sXT[i * 264 + hf * 128 + wr * 64 + mf * 16 + lg * 4];
          msgr[hf][mf][0] += xv * w0;
          msgr[hf][mf][1] += xv * w1;
        }
    }
  }

  // ---- epilogue: lane owns (row, o) pairs; scatter partial to agg[dst] ----
  #pragma unroll
  for (int hf = 0; hf < 2; ++hf)
    #pragma unroll
    for (int nf = 0; nf < 2; ++nf) {
      const int o = ((FOUT == 64) ? (wc * 2 + nf) * 16 : nf * 16) + ll;
      #pragma unroll
      for (int mf = 0; mf < 4; ++mf)
        #pragma unroll
        for (int r = 0; r < 4; ++r) {
          int row = hf * 128 + wr * 64 + mf * 16 + lg * 4 + r;
          int d = sDst[row];
          if (d >= 0) atomicAdd(&agg[(size_t)d * FOUT + o], msgr[hf][mf][nf][r]);
        }
    }
}

// ---------------- node update / pool / MLP ----------------

__global__ void k_node1(const float* __restrict__ x, const float* __restrict__ agg,
                        const int* __restrict__ cnt, const float* __restrict__ root,
                        const float* __restrict__ bias, float* __restrict__ h) {
  int tid = blockIdx.x * 256 + threadIdx.x;
  if (tid >= NV_N * 32) return;
  int n = tid >> 5, j = tid & 31;
  const float* xr = x + n * 32;
  float s = 0.f;
  #pragma unroll
  for (int i = 0; i < 32; ++i) s = fmaf(xr[i], root[i * 32 + j], s);
  int c = cnt[n]; if (c < 1) c = 1;
  h[tid] = fmaxf(agg[tid] / (float)c + s + bias[j], 0.f);
}

__global__ void k_node2(const float* __restrict__ hin, const float* __restrict__ agg,
                        const int* __restrict__ cnt, const float* __restrict__ root,
                        const float* __restrict__ bias, float* __restrict__ h2) {
  int tid = blockIdx.x * 256 + threadIdx.x;
  if (tid >= NV_N * 64) return;
  int n = tid >> 6, j = tid & 63;
  const float* xr = hin + n * 32;
  float s = 0.f;
  #pragma unroll
  for (int i = 0; i < 32; ++i) s = fmaf(xr[i], root[i * 64 + j], s);
  int c = cnt[n]; if (c < 1) c = 1;
  h2[tid] = fmaxf(agg[tid] / (float)c + s + bias[j], 0.f);
}

__device__ __forceinline__ int lowerb(const int* __restrict__ a, int n, int key) {
  int lo = 0, hi = n;
  while (lo < hi) { int mid = (lo + hi) >> 1; if (a[mid] < key) lo = mid + 1; else hi = mid; }
  return lo;
}

__global__ void k_pool(const float* __restrict__ h2, const int* __restrict__ batch,
                       float* __restrict__ g) {
  int gid = (blockIdx.x * 256 + threadIdx.x) >> 6;
  int l = threadIdx.x & 63;
  if (gid >= NG_N) return;
  int lo = lowerb(batch, NV_N, gid);
  int hi = lowerb(batch, NV_N, gid + 1);
  float s = 0.f;
  for (int n = lo; n < hi; ++n) s += h2[n * 64 + l];
  int c = hi - lo; if (c < 1) c = 1;
  g[gid * 64 + l] = s / (float)c;
}

template<int K, bool RELU>
__global__ void k_fc(const float* __restrict__ A, const float* __restrict__ W,
                     const float* __restrict__ bias, float* __restrict__ out, int N) {
  __shared__ float sA[8][K];
  int r0 = blockIdx.x * 8;
  int n = blockIdx.y * 256 + threadIdx.x;
  for (int j = threadIdx.x; j < 8 * K; j += 256) {
    int rr = j / K, kk = j - rr * K;
    int r = r0 + rr;
    sA[rr][kk] = (r < NG_N) ? A[r * K + kk] : 0.f;
  }
  __syncthreads();
  float acc[8] = {0.f, 0.f, 0.f, 0.f, 0.f, 0.f, 0.f, 0.f};
  for (int k = 0; k < K; ++k) {
    float b = W[k * N + n];
    #pragma unroll
    for (int rr = 0; rr < 8; ++rr) acc[rr] = fmaf(sA[rr][k], b, acc[rr]);
  }
  float bs = bias[n];
  #pragma unroll
  for (int rr = 0; rr < 8; ++rr) {
    int r = r0 + rr;
    if (r < NG_N) {
      float v = acc[rr] + bs;
      if (RELU) v = fmaxf(v, 0.f);
      out[r * N + n] = v;
    }
  }
}

__global__ void k_fc4(const float* __restrict__ A, const float* __restrict__ W,
                      const float* __restrict__ bias, float* __restrict__ out) {
  int tid = blockIdx.x * 256 + threadIdx.x;
  int r = tid >> 2, s = tid & 3;
  if (r >= NG_N || s >= 3) return;
  float acc = bias[s];
  for (int k = 0; k < 256; ++k) acc = fmaf(A[r * 256 + k], W[k * 3 + s], acc);
  out[r * 3 + s] = acc;
}

// ---------------- launch ----------------

extern "C" void kernel_launch(void* const* d_in, const int* in_sizes, int n_in,
                              void* d_out, int out_size, void* d_ws, size_t ws_size,
                              hipStream_t stream) {
  const float* x     = (const float*)d_in[0];
  const int*   ei    = (const int*)d_in[1];
  const int*   eap   = (const int*)d_in[2];
  const int*   batch = (const int*)d_in[3];
  const float* W1a   = (const float*)d_in[4];
  const float* b1a   = (const float*)d_in[5];
  const float* W1b   = (const float*)d_in[6];
  const float* b1b   = (const float*)d_in[7];
  const float* W2a   = (const float*)d_in[8];
  const float* b2a   = (const float*)d_in[9];
  const float* W2b   = (const float*)d_in[10];
  const float* b2b   = (const float*)d_in[11];
  const float* root1 = (const float*)d_in[12];
  const float* bias1 = (const float*)d_in[13];
  const float* root2 = (const float*)d_in[14];
  const float* bias2 = (const float*)d_in[15];
  const float* fcW1  = (const float*)d_in[16];
  const float* fcb1  = (const float*)d_in[17];
  const float* fcW2  = (const float*)d_in[18];
  const float* fcb2  = (const float*)d_in[19];
  const float* fcW3  = (const float*)d_in[20];
  const float* fcb3  = (const float*)d_in[21];
  const float* fcW4  = (const float*)d_in[22];
  const float* fcb4  = (const float*)d_in[23];
  float* out = (float*)d_out;

  char* w = (char*)d_ws;
  size_t off = 0;
  auto take = [&](size_t bytes) -> void* {
    void* p = w + off;
    off = (off + bytes + 255) & ~(size_t)255;
    return p;
  };
  unsigned short* tabs = (unsigned short*)take(4 * 256 * 1024 * 2);
  unsigned short* w1p  = (unsigned short*)take((size_t)1024 * 1024 * 2 + 65536);
  unsigned short* w2p  = (unsigned short*)take((size_t)1024 * 2048 * 2 + 65536);
  float* agg1 = (float*)take((size_t)NV_N * 32 * 4);
  float* agg2 = (float*)take((size_t)NV_N * 64 * 4);
  int*   cnt  = (int*)take((size_t)NV_N * 4);
  float* h    = (float*)take((size_t)NV_N * 32 * 4);
  float* h2   = (float*)take((size_t)NV_N * 64 * 4);
  float* g    = (float*)take((size_t)NG_N * 64 * 4);
  float* l1   = (float*)take((size_t)NG_N * 512 * 4);
  float* l2   = (float*)take((size_t)NG_N * 512 * 4);
  float* l3   = (float*)take((size_t)NG_N * 256 * 4);

  hipMemsetAsync(agg1, 0, (size_t)NV_N * 32 * 4, stream);
  hipMemsetAsync(agg2, 0, (size_t)NV_N * 64 * 4, stream);
  hipMemsetAsync(cnt, 0, (size_t)NV_N * 4, stream);

  k_tables<<<4096, 256, 0, stream>>>(W1a, b1a, W2a, b2a, tabs);
  k_pack<<<(1024 * 1024 / 8 + 255) / 256, 256, 0, stream>>>(W1b, w1p, 1024);
  k_pack<<<(1024 * 2048 / 8 + 255) / 256, 256, 0, stream>>>(W2b, w2p, 2048);
  k_count<<<(E_N + 255) / 256, 256, 0, stream>>>(ei, cnt);

  const int nblk = 3 * NBIG + 4 * (NTILES - NBIG);   // 1536 = 3*512 units
  k_edge<1024, 32><<<nblk, 256, 0, stream>>>(x, ei, eap, tabs, tabs + 262144,
                                             w1p, b1b, agg1);
  k_node1<<<(NV_N * 32) / 256, 256, 0, stream>>>(x, agg1, cnt, root1, bias1, h);

  k_edge<2048, 64><<<nblk, 256, 0, stream>>>(h, ei, eap, tabs + 2 * 262144, tabs + 3 * 262144,
                                             w2p, b2b, agg2);
  k_node2<<<(NV_N * 64) / 256, 256, 0, stream>>>(h, agg2, cnt, root2, bias2, h2);

  k_pool<<<(NG_N * 64) / 256, 256, 0, stream>>>(h2, batch, g);

  k_fc<64, true><<<dim3((NG_N + 7) / 8, 2), 256, 0, stream>>>(g, fcW1, fcb1, l1, 512);
  k_fc<512, true><<<dim3((NG_N + 7) / 8, 2), 256, 0, stream>>>(l1, fcW2, fcb2, l2, 512);
  k_fc<512, true><<<dim3((NG_N + 7) / 8, 1), 256, 0, stream>>>(l2, fcW3, fcb3, l3, 256);
  k_fc4<<<(NG_N * 4 + 255) / 256, 256, 0, stream>>>(l3, fcW4, fcb4, out);
}